// Round 9
// baseline (461.802 us; speedup 1.0000x reference)
//
#include <hip/hip_runtime.h>

#define NN 50000
#define NE 800000
#define IN_C 256
#define HID_C 256
#define OUT_C 128
#define NB 196      // ceil(NN/256)
#define NEB 391     // ceil(NE/(8*256))
#define MAGIC 0x5EED5EED

typedef unsigned short u16;
typedef __attribute__((ext_vector_type(8))) short short8;
typedef __attribute__((ext_vector_type(8))) unsigned short ushort8;
typedef __attribute__((ext_vector_type(4))) float f32x4;

__device__ __forceinline__ u16 f2b(float f) {
  unsigned int u = __float_as_uint(f);
  return (u16)((u + 0x7FFFu + ((u >> 16) & 1u)) >> 16);  // RNE
}
__device__ __forceinline__ float b2f(u16 s) {
  return __uint_as_float(((unsigned int)s) << 16);
}

__device__ __forceinline__ void gate_set(int* g) {
  __hip_atomic_store(g, MAGIC, __ATOMIC_RELEASE, __HIP_MEMORY_SCOPE_AGENT);
}
__device__ __forceinline__ void gate_wait(const int* g) {
  while (__hip_atomic_load(g, __ATOMIC_ACQUIRE, __HIP_MEMORY_SCOPE_AGENT) != MAGIC) {}
}

// ---------------- K1: convw + cnt-zero + hist (gated), no LDS ----------------

__global__ __launch_bounds__(256) void k1_setup(const float* __restrict__ W1,
                                                const float* __restrict__ W2,
                                                u16* __restrict__ W1t,
                                                u16* __restrict__ W2t,
                                                const int* __restrict__ col,
                                                int* __restrict__ cnt,
                                                int* __restrict__ zgate) {
  int b = blockIdx.x;
  int t = threadIdx.x;
  if (b < 256) {
    int id = b * 256 + t;
    int n = id >> 8, k = id & 255;
    W1t[id] = f2b(W1[k * 256 + n]);
    if (id < 128 * 256) W2t[id] = f2b(W2[k * 128 + n]);
  } else if (b < 256 + NB) {
    int sb = b - 256;
    int i = sb * 256 + t;
    if (i < NN) cnt[i] = 0;
    __threadfence();
    __syncthreads();
    if (t == 0) gate_set(&zgate[sb]);
  } else {
    if (t < NB) gate_wait(&zgate[t]);
    __syncthreads();
    const int T = NEB * 256;
    int idx = (b - 256 - NB) * 256 + t;
#pragma unroll
    for (int i = 0; i < 8; ++i) {
      int e = idx + i * T;
      if (e < NE) atomicAdd(&cnt[col[e]], 1);
    }
  }
}

// ---------------- MFMA GEMM body, row-scaled epilogue ----------------
// C[r,:]bf16 = scale(r) * (A[r,:] @ Bt^T).  BM=BN=128, BK=32, 4 waves 2x2,
// register prefetch + double-buffered LDS, one barrier per K-iter.
// SCALE_FROM_CNT: scale = rsqrtf(cnt[r]+1) (cnt final); else scale = dinv[r].

template <bool A_IS_F32, bool SCALE_FROM_CNT>
__device__ __forceinline__ void gemm_body(const void* __restrict__ Ap,
                                          const u16* __restrict__ Bt,
                                          const void* __restrict__ scale_src,
                                          u16* __restrict__ C, int M, int N,
                                          int bx, int by,
                                          u16 (&Asl)[2][5120], u16 (&Bsl)[2][5120]) {
  const int tid = threadIdx.x;
  const int row0 = by * 128;
  const int col0 = bx * 128;

  f32x4 acc[4][4] = {};

  const int seg = tid & 7;
  const int rb = tid >> 3;
  const int wave = tid >> 6, lane = tid & 63;
  const int wm = wave >> 1, wn = wave & 1;
  const int qr = lane & 15, quad = lane >> 4;

  float4 aF[4];
  ushort4 aU[4];
  ushort4 bR[4];

  auto load_tiles = [&](int k0) {
    if constexpr (A_IS_F32) {
      const float* A = (const float*)Ap;
#pragma unroll
      for (int i = 0; i < 4; ++i) {
        int gr = row0 + rb + i * 32;
        aF[i] = (gr < M) ? *(const float4*)&A[(size_t)gr * 256 + k0 + seg * 4]
                         : make_float4(0.f, 0.f, 0.f, 0.f);
      }
    } else {
      const u16* A = (const u16*)Ap;
#pragma unroll
      for (int i = 0; i < 4; ++i) {
        int gr = row0 + rb + i * 32;
        aU[i] = (gr < M) ? *(const ushort4*)&A[(size_t)gr * 256 + k0 + seg * 4]
                         : make_ushort4(0, 0, 0, 0);
      }
    }
#pragma unroll
    for (int i = 0; i < 4; ++i) {
      int n = rb + i * 32;
      bR[i] = *(const ushort4*)&Bt[(size_t)(col0 + n) * 256 + k0 + seg * 4];
    }
  };

  auto write_lds = [&](int buf) {
#pragma unroll
    for (int i = 0; i < 4; ++i) {
      int r = rb + i * 32;
      ushort4 u;
      if constexpr (A_IS_F32) {
        u.x = f2b(aF[i].x); u.y = f2b(aF[i].y);
        u.z = f2b(aF[i].z); u.w = f2b(aF[i].w);
      } else {
        u = aU[i];
      }
      *(ushort4*)&Asl[buf][r * 40 + seg * 4] = u;
      *(ushort4*)&Bsl[buf][r * 40 + seg * 4] = bR[i];
    }
  };

  load_tiles(0);
  write_lds(0);
  __syncthreads();

#pragma unroll
  for (int it = 0; it < 8; ++it) {
    const int cur = it & 1;
    if (it < 7) load_tiles((it + 1) * 32);

    short8 afr[4], bfr[4];
#pragma unroll
    for (int mt = 0; mt < 4; ++mt)
      afr[mt] = *(const short8*)&Asl[cur][(wm * 64 + mt * 16 + qr) * 40 + quad * 8];
#pragma unroll
    for (int nt = 0; nt < 4; ++nt)
      bfr[nt] = *(const short8*)&Bsl[cur][(wn * 64 + nt * 16 + qr) * 40 + quad * 8];
#pragma unroll
    for (int mt = 0; mt < 4; ++mt)
#pragma unroll
      for (int nt = 0; nt < 4; ++nt)
        acc[mt][nt] = __builtin_amdgcn_mfma_f32_16x16x32_bf16(afr[mt], bfr[nt], acc[mt][nt], 0, 0, 0);

    if (it < 7) {
      write_lds(1 - cur);
      __syncthreads();
    }
  }

#pragma unroll
  for (int mt = 0; mt < 4; ++mt) {
#pragma unroll
    for (int i = 0; i < 4; ++i) {
      int gr = row0 + wm * 64 + mt * 16 + quad * 4 + i;
      if (gr < M) {
        float sc;
        if constexpr (SCALE_FROM_CNT)
          sc = rsqrtf((float)(((const int*)scale_src)[gr] + 1));
        else
          sc = ((const float*)scale_src)[gr];
#pragma unroll
        for (int nt = 0; nt < 4; ++nt) {
          int gc = col0 + wn * 64 + nt * 16 + qr;
          C[(size_t)gr * N + gc] = f2b(acc[mt][nt][i] * sc);
        }
      }
    }
  }
}

// ---------------- K2: merged scan (gated) + scatter (gated) + GEMM1 ----------------
// blocks [0,NB): scan; [NB, NB+NEB): scatter; [NB+NEB, +782): GEMM1.
// GEMM1 never spins (scale from cnt). Spinners (scatter, 391) < slots (1024):
// deadlock-free regardless of dispatch order.

__global__ __launch_bounds__(256) void k2_scan_scatter_gemm1(
    const int* __restrict__ cnt, int* __restrict__ bsum, int* __restrict__ sgate,
    int* __restrict__ row_off, int* __restrict__ cursor, float* __restrict__ dinv,
    int* __restrict__ cgate, const int* __restrict__ row, const int* __restrict__ col,
    int* __restrict__ csr, const float* __restrict__ x, const u16* __restrict__ W1t,
    u16* __restrict__ Hb) {
  __shared__ u16 Asl[2][5120];
  __shared__ u16 Bsl[2][5120];
  int b = blockIdx.x;
  int t = threadIdx.x;
  if (b < NB) {
    __shared__ int wsum[4], wpre[5], ws2[4];
    int lane = t & 63, wid = t >> 6;
    int i = b * 256 + t;
    int v = (i < NN) ? cnt[i] : 0;
    int s = v;
#pragma unroll
    for (int off = 1; off < 64; off <<= 1) {
      int tt = __shfl_up(s, off, 64);
      if (lane >= off) s += tt;
    }
    if (lane == 63) wsum[wid] = s;
    __syncthreads();
    if (t == 0) {
      int acc = 0;
#pragma unroll
      for (int w = 0; w < 4; ++w) { wpre[w] = acc; acc += wsum[w]; }
      wpre[4] = acc;
    }
    __syncthreads();
    if (t == 0) {
      bsum[b] = wpre[4];
      __threadfence();
      gate_set(&sgate[b]);
    }
    // prefix over lower blocks
    int bv = 0;
    if (t < b) {
      gate_wait(&sgate[t]);
      bv = bsum[t];
    }
#pragma unroll
    for (int off = 32; off > 0; off >>= 1) bv += __shfl_down(bv, off, 64);
    if (lane == 0) ws2[wid] = bv;
    __syncthreads();
    int boffs = ws2[0] + ws2[1] + ws2[2] + ws2[3];
    if (i < NN) {
      int off = boffs + wpre[wid] + (s - v);
      row_off[i] = off;
      cursor[i] = off;
      dinv[i] = rsqrtf((float)(v + 1));
    }
    if (b == 0 && t == 0) row_off[NN] = NE;
    __threadfence();
    __syncthreads();
    if (t == 0) gate_set(&cgate[b]);
  } else if (b < NB + NEB) {
    if (t < NB) gate_wait(&cgate[t]);
    __syncthreads();
    const int T = NEB * 256;
    int idx = (b - NB) * 256 + t;
#pragma unroll
    for (int i = 0; i < 8; ++i) {
      int e = idx + i * T;
      if (e < NE) {
        int c = col[e];
        int p = atomicAdd(&cursor[c], 1);
        __builtin_nontemporal_store(row[e], &csr[p]);
      }
    }
  } else {
    int gb = b - NB - NEB;
    gemm_body<true, true>(x, W1t, cnt, Hb, NN, HID_C, gb & 1, gb >> 1, Asl, Bsl);
  }
}

// plain GEMM kernel (layer 2), scale = dinv
__global__ __launch_bounds__(256) void gemm_mfma2(const u16* __restrict__ Ap,
                                                  const u16* __restrict__ Bt,
                                                  const float* __restrict__ dinv,
                                                  u16* __restrict__ C, int M, int N) {
  __shared__ u16 Asl[2][5120];
  __shared__ u16 Bsl[2][5120];
  gemm_body<false, false>(Ap, Bt, dinv, C, M, N, blockIdx.x, blockIdx.y, Asl, Bsl);
}

// ---------------- aggregation: weightless sum of pre-scaled rows ----------------

__global__ __launch_bounds__(256) void agg256_bf(const u16* __restrict__ h,
                                                 const int* __restrict__ row_off,
                                                 const int* __restrict__ csr,
                                                 const float* __restrict__ dinv,
                                                 const float* __restrict__ bias,
                                                 u16* __restrict__ out, int n) {
  int wave = threadIdx.x >> 6;
  int lane = threadIdx.x & 63;
  int half = lane >> 5;
  int sl = lane & 31;
  int v = blockIdx.x * 8 + wave * 2 + half;
  if (v >= n) return;
  int beg = row_off[v], end = row_off[v + 1];
  float a[8] = {};
  int e = beg;
  for (; e < end && (e & 3); ++e) {
    int s0 = csr[e];
    ushort8 g0 = *(const ushort8*)&h[(size_t)s0 * 256 + sl * 8];
#pragma unroll
    for (int i = 0; i < 8; ++i) a[i] += b2f((u16)g0[i]);
  }
  for (; e + 7 < end; e += 8) {
    int4 i0 = *(const int4*)&csr[e];
    int4 i1 = *(const int4*)&csr[e + 4];
    int s[8] = {i0.x, i0.y, i0.z, i0.w, i1.x, i1.y, i1.z, i1.w};
    ushort8 g[8];
#pragma unroll
    for (int j = 0; j < 8; ++j)
      g[j] = *(const ushort8*)&h[(size_t)s[j] * 256 + sl * 8];
#pragma unroll
    for (int j = 0; j < 8; ++j)
#pragma unroll
      for (int i = 0; i < 8; ++i) a[i] += b2f((u16)g[j][i]);
  }
  for (; e < end; ++e) {
    int s0 = csr[e];
    ushort8 g0 = *(const ushort8*)&h[(size_t)s0 * 256 + sl * 8];
#pragma unroll
    for (int i = 0; i < 8; ++i) a[i] += b2f((u16)g0[i]);
  }
  ushort8 hs = *(const ushort8*)&h[(size_t)v * 256 + sl * 8];
#pragma unroll
  for (int i = 0; i < 8; ++i) a[i] += b2f((u16)hs[i]);
  float dv = dinv[v];
  float4 bv0 = *(const float4*)&bias[sl * 8];
  float4 bv1 = *(const float4*)&bias[sl * 8 + 4];
  float bb[8] = {bv0.x, bv0.y, bv0.z, bv0.w, bv1.x, bv1.y, bv1.z, bv1.w};
  ushort8 o;
#pragma unroll
  for (int i = 0; i < 8; ++i) {
    float r = fmaxf(a[i] * dv + bb[i], 0.f);
    o[i] = (short)f2b(r);
  }
  *(ushort8*)&out[(size_t)v * 256 + sl * 8] = o;
}

__global__ __launch_bounds__(256) void agg128_bf(const u16* __restrict__ h,
                                                 const int* __restrict__ row_off,
                                                 const int* __restrict__ csr,
                                                 const float* __restrict__ dinv,
                                                 const float* __restrict__ bias,
                                                 float* __restrict__ out, int n) {
  int wave = threadIdx.x >> 6;
  int lane = threadIdx.x & 63;
  int quarter = lane >> 4;
  int sl = lane & 15;
  int v = blockIdx.x * 16 + wave * 4 + quarter;
  if (v >= n) return;
  int beg = row_off[v], end = row_off[v + 1];
  float a[8] = {};
  int e = beg;
  for (; e < end && (e & 3); ++e) {
    int s0 = csr[e];
    ushort8 g0 = *(const ushort8*)&h[(size_t)s0 * 128 + sl * 8];
#pragma unroll
    for (int i = 0; i < 8; ++i) a[i] += b2f((u16)g0[i]);
  }
  for (; e + 7 < end; e += 8) {
    int4 i0 = *(const int4*)&csr[e];
    int4 i1 = *(const int4*)&csr[e + 4];
    int s[8] = {i0.x, i0.y, i0.z, i0.w, i1.x, i1.y, i1.z, i1.w};
    ushort8 g[8];
#pragma unroll
    for (int j = 0; j < 8; ++j)
      g[j] = *(const ushort8*)&h[(size_t)s[j] * 128 + sl * 8];
#pragma unroll
    for (int j = 0; j < 8; ++j)
#pragma unroll
      for (int i = 0; i < 8; ++i) a[i] += b2f((u16)g[j][i]);
  }
  for (; e < end; ++e) {
    int s0 = csr[e];
    ushort8 g0 = *(const ushort8*)&h[(size_t)s0 * 128 + sl * 8];
#pragma unroll
    for (int i = 0; i < 8; ++i) a[i] += b2f((u16)g0[i]);
  }
  ushort8 hs = *(const ushort8*)&h[(size_t)v * 128 + sl * 8];
#pragma unroll
  for (int i = 0; i < 8; ++i) a[i] += b2f((u16)hs[i]);
  float dv = dinv[v];
  float4 bv0 = *(const float4*)&bias[sl * 8];
  float4 bv1 = *(const float4*)&bias[sl * 8 + 4];
  float bb[8] = {bv0.x, bv0.y, bv0.z, bv0.w, bv1.x, bv1.y, bv1.z, bv1.w};
  float o[8];
#pragma unroll
  for (int i = 0; i < 8; ++i) o[i] = a[i] * dv + bb[i];
  *(float4*)&out[(size_t)v * 128 + sl * 8] = make_float4(o[0], o[1], o[2], o[3]);
  *(float4*)&out[(size_t)v * 128 + sl * 8 + 4] = make_float4(o[4], o[5], o[6], o[7]);
}

// ---------------- launch ----------------

extern "C" void kernel_launch(void* const* d_in, const int* in_sizes, int n_in,
                              void* d_out, int out_size, void* d_ws, size_t ws_size,
                              hipStream_t stream) {
  const float* x = (const float*)d_in[0];
  const int* ei = (const int*)d_in[1];
  const float* W1 = (const float*)d_in[2];
  const float* b1 = (const float*)d_in[3];
  const float* W2 = (const float*)d_in[4];
  const float* b2 = (const float*)d_in[5];
  float* out = (float*)d_out;

  const int* row = ei;
  const int* col = ei + NE;

  // workspace layout — all segments 16B-multiple so csr stays 16B-aligned
  u16* Hb = (u16*)d_ws;                       // [NN,256] bf16, pre-scaled by dinv[row]
  u16* H2b = Hb + (size_t)NN * 256;           // [NN,256] bf16
  u16* H3b = H2b + (size_t)NN * 256;          // [NN,128] bf16, pre-scaled
  u16* W1t = H3b + (size_t)NN * 128;          // [256,256] bf16
  u16* W2t = W1t + 256 * 256;                 // [128,256] bf16
  int* cnt = (int*)(W2t + 128 * 256);         // [NN]
  int* row_off = cnt + NN;                    // [NN+4]
  int* cursor = row_off + NN + 4;             // [NN]
  float* dinv = (float*)(cursor + NN);        // [NN]
  int* bsum = (int*)(dinv + NN);              // [256]
  int* zgate = bsum + 256;                    // [256] poisoned 0xAA -> != MAGIC
  int* sgate = zgate + 256;                   // [256]
  int* cgate = sgate + 256;                   // [256]
  int* csr = cgate + 256;                     // [NE] src only, 16B-aligned

  // K1: weight convert + cnt zero + degree hist (gated), 843 blocks all resident
  k1_setup<<<256 + NB + NEB, 256, 0, stream>>>(W1, W2, W1t, W2t, col, cnt, zgate);

  // K2: scan (196) + scatter (391, gated on scan) + GEMM1 (782, scale from cnt)
  k2_scan_scatter_gemm1<<<NB + NEB + 782, 256, 0, stream>>>(
      cnt, bsum, sgate, row_off, cursor, dinv, cgate, row, col, csr, x, W1t, Hb);

  // K3
  agg256_bf<<<(NN + 7) / 8, 256, 0, stream>>>(Hb, row_off, csr, dinv, b1, H2b, NN);

  // K4
  {
    dim3 grid(OUT_C / 128, (NN + 127) / 128);
    gemm_mfma2<<<grid, 256, 0, stream>>>(H2b, W2t, dinv, H3b, NN, OUT_C);
  }

  // K5
  agg128_bf<<<(NN + 15) / 16, 256, 0, stream>>>(H3b, row_off, csr, dinv, b2, out, NN);
}